// Round 2
// baseline (662.997 us; speedup 1.0000x reference)
//
#include <hip/hip_runtime.h>
#include <hip/hip_bf16.h>
#include <stdint.h>

#define NEXP 8
#define HD 1024
#define ID 3584
#define NTOK 2048
#define NSLOT 4096          // NTOK * TOPK
#define SLOT_PAD 128
#define NSLOT_ALLOC (NSLOT + SLOT_PAD)

typedef unsigned short u16;
typedef __attribute__((ext_vector_type(8))) short s16x8;
typedef __attribute__((ext_vector_type(4))) short s16x4;
typedef __attribute__((ext_vector_type(4))) float f32x4;
typedef __attribute__((ext_vector_type(4))) int   i32x4;

__device__ __forceinline__ u16 f2bf(float f) {
    __hip_bfloat16 h = __float2bfloat16(f);   // RNE; compiler emits good cvt code (m240)
    union { __hip_bfloat16 h; u16 u; } v; v.h = h; return v.u;
}

__device__ __forceinline__ s16x8 cvt8(f32x4 a, f32x4 b) {
    s16x8 o;
    o[0]=(short)f2bf(a[0]); o[1]=(short)f2bf(a[1]); o[2]=(short)f2bf(a[2]); o[3]=(short)f2bf(a[3]);
    o[4]=(short)f2bf(b[0]); o[5]=(short)f2bf(b[1]); o[6]=(short)f2bf(b[2]); o[7]=(short)f2bf(b[3]);
    return o;
}

__device__ __forceinline__ void glds16(const void* g, void* l) {
    __builtin_amdgcn_global_load_lds((const __attribute__((address_space(1))) unsigned*)g,
                                     (__attribute__((address_space(3))) unsigned*)l, 16, 0, 0);
}

// ---------------- K0: zero counters ----------------
__global__ void init_kernel(int* __restrict__ counts) {
    if (threadIdx.x < 16) counts[threadIdx.x] = 0;   // counts[8] + counts2[8]
}

// ---------------- K1: router (fp32, exact top-2) ----------------
__global__ void router_kernel(const float* __restrict__ x, const float* __restrict__ wg,
                              int* __restrict__ topk_idx, float* __restrict__ topk_w,
                              int* __restrict__ counts) {
    int t = blockIdx.x;
    int lane = threadIdx.x;   // 64 threads = 1 wave
    const float* xr = x + (size_t)t * HD;
    float acc[NEXP];
#pragma unroll
    for (int e = 0; e < NEXP; ++e) acc[e] = 0.f;
#pragma unroll
    for (int i = 0; i < HD / 256; ++i) {   // 4 iters, f32x4 per lane
        int h = i * 256 + lane * 4;
        f32x4 xv = *(const f32x4*)(xr + h);
#pragma unroll
        for (int e = 0; e < NEXP; ++e) {
            f32x4 wv = *(const f32x4*)(wg + e * HD + h);
            acc[e] += xv[0]*wv[0] + xv[1]*wv[1] + xv[2]*wv[2] + xv[3]*wv[3];
        }
    }
#pragma unroll
    for (int e = 0; e < NEXP; ++e) {
#pragma unroll
        for (int s = 32; s > 0; s >>= 1) acc[e] += __shfl_xor(acc[e], s, 64);
    }
    if (lane == 0) {
        int b0 = 0; float l0 = acc[0];
#pragma unroll
        for (int e = 1; e < NEXP; ++e) if (acc[e] > l0) { l0 = acc[e]; b0 = e; }
        int b1 = (b0 == 0) ? 1 : 0; float l1 = acc[b1];
#pragma unroll
        for (int e = 0; e < NEXP; ++e) {
            if (e == b0 || e == b1) continue;
            if (acc[e] > l1) { l1 = acc[e]; b1 = e; }
        }
        float w0 = 1.f / (1.f + expf(l1 - l0));   // renormalized top-2 softmax
        float w1 = 1.f - w0;
        topk_idx[2 * t] = b0; topk_idx[2 * t + 1] = b1;
        topk_w[2 * t] = w0;  topk_w[2 * t + 1] = w1;
        atomicAdd(&counts[b0], 1);
        atomicAdd(&counts[b1], 1);
    }
}

// ---------------- K2: exclusive scan + pad rows ----------------
__global__ void scan_kernel(const int* __restrict__ counts, int* __restrict__ offsets,
                            int* __restrict__ rows) {
    if (threadIdx.x == 0) {
        int off = 0;
#pragma unroll
        for (int e = 0; e < NEXP; ++e) { offsets[e] = off; off += counts[e]; }
    }
    if (threadIdx.x < SLOT_PAD) rows[NSLOT + threadIdx.x] = 0;
}

// ---------------- K3: slot assignment ----------------
__global__ void assign_kernel(const int* __restrict__ topk_idx, const int* __restrict__ offsets,
                              int* __restrict__ counts2, int* __restrict__ rows,
                              int* __restrict__ slot_of) {
    int i = blockIdx.x * 256 + threadIdx.x;   // 0..4095
    int e = topk_idx[i];
    int pos = atomicAdd(&counts2[e], 1);
    int slot = offsets[e] + pos;
    rows[slot] = i >> 1;       // token id
    slot_of[i] = slot;
}

// ---------------- K4: x fp32 -> bf16 ----------------
__global__ void cvt_x_kernel(const float* __restrict__ x, u16* __restrict__ xbf) {
    int i = blockIdx.x * 256 + threadIdx.x;   // each handles 4 floats
    f32x4 v = ((const f32x4*)x)[i];
    s16x4 o;
#pragma unroll
    for (int j = 0; j < 4; ++j) o[j] = (short)f2bf(v[j]);
    ((s16x4*)xbf)[i] = o;
}

// ---------------- K5: fused GEMM1 (g,u) + SwiGLU -> h (bf16) ----------------
// 128x128 tile, BK=32, k-slab LDS [4][128][8] (conflict-free, glds-compatible),
// double-buffered single-barrier pipeline, async-stage split for B (fp32->bf16 in regs).
__global__ __launch_bounds__(256, 2)
void gemm1_kernel(const u16* __restrict__ xbf, const float* __restrict__ w1,
                  const float* __restrict__ w3, const int* __restrict__ counts,
                  const int* __restrict__ offsets, const int* __restrict__ rows,
                  u16* __restrict__ hbuf) {
    const int NT = ID / 128;      // 28
    const int MT = NTOK / 128;    // 16
    int bid = blockIdx.x;
    int e = bid / (MT * NT);
    int rem = bid - e * (MT * NT);
    int mt = rem / NT;
    int nt = rem - mt * NT;
    int n_e = counts[e];
    int m0 = mt * 128;
    if (m0 >= n_e) return;
    int off = offsets[e];
    int n0 = nt * 128;

    __shared__ u16 As[2][4][128][8];    // 16 KB
    __shared__ u16 B1s[2][4][128][8];   // 16 KB
    __shared__ u16 B3s[2][4][128][8];   // 16 KB

    int tid = threadIdx.x;
    int lane = tid & 63;
    int wid = tid >> 6;

    // A staging via global_load_lds: wave `wid` fills k-slab `wid`, rows {lane, 64+lane}
    int tokA0 = rows[off + m0 + lane];
    int tokA1 = rows[off + m0 + 64 + lane];
    const u16* srcA0 = xbf + (size_t)tokA0 * HD + wid * 8;
    const u16* srcA1 = xbf + (size_t)tokA1 * HD + wid * 8;

    // B staging: thread covers row tid>>1, k range (tid&1)*16 .. +16 (both matrices)
    int brow = tid >> 1;
    int bs0 = (tid & 1) * 2;           // first k-slab this thread writes
    const float* pB1 = w1 + ((size_t)e * ID + n0 + brow) * HD + (tid & 1) * 16;
    const float* pB3 = w3 + ((size_t)e * ID + n0 + brow) * HD + (tid & 1) * 16;

    f32x4 accg[4][4] = {}, accu[4][4] = {};
    int wm = (wid >> 1) * 64, wn = (wid & 1) * 64;
    int lr = lane & 15, k8 = lane >> 4;

    f32x4 r1[4], r3[4];

    // prologue: stage tile 0 into buf 0
    glds16(srcA0, &As[0][wid][0][0]);
    glds16(srcA1, &As[0][wid][64][0]);
#pragma unroll
    for (int j = 0; j < 4; ++j) { r1[j] = *(const f32x4*)(pB1 + 4 * j); r3[j] = *(const f32x4*)(pB3 + 4 * j); }
    *(s16x8*)&B1s[0][bs0    ][brow][0] = cvt8(r1[0], r1[1]);
    *(s16x8*)&B1s[0][bs0 + 1][brow][0] = cvt8(r1[2], r1[3]);
    *(s16x8*)&B3s[0][bs0    ][brow][0] = cvt8(r3[0], r3[1]);
    *(s16x8*)&B3s[0][bs0 + 1][brow][0] = cvt8(r3[2], r3[3]);
    __syncthreads();

    const int NIT = HD / 32;  // 32
    for (int it = 0; it < NIT; ++it) {
        int cur = it & 1, nxt = cur ^ 1;
        bool more = (it + 1) < NIT;
        int kn = (it + 1) * 32;
        if (more) {   // issue next-tile loads EARLY (latency hides under MFMA)
            glds16(srcA0 + kn, &As[nxt][wid][0][0]);
            glds16(srcA1 + kn, &As[nxt][wid][64][0]);
#pragma unroll
            for (int j = 0; j < 4; ++j) { r1[j] = *(const f32x4*)(pB1 + kn + 4 * j); r3[j] = *(const f32x4*)(pB3 + kn + 4 * j); }
        }
        s16x8 a[4], b1[4], b3[4];
#pragma unroll
        for (int f = 0; f < 4; ++f) {
            a[f]  = *(const s16x8*)&As[cur][k8][wm + f * 16 + lr][0];
            b1[f] = *(const s16x8*)&B1s[cur][k8][wn + f * 16 + lr][0];
            b3[f] = *(const s16x8*)&B3s[cur][k8][wn + f * 16 + lr][0];
        }
#pragma unroll
        for (int fm = 0; fm < 4; ++fm)
#pragma unroll
            for (int fn = 0; fn < 4; ++fn) {
                accg[fm][fn] = __builtin_amdgcn_mfma_f32_16x16x32_bf16(a[fm], b1[fn], accg[fm][fn], 0, 0, 0);
                accu[fm][fn] = __builtin_amdgcn_mfma_f32_16x16x32_bf16(a[fm], b3[fn], accu[fm][fn], 0, 0, 0);
            }
        if (more) {   // convert + write LATE, after MFMA covered the load latency
            *(s16x8*)&B1s[nxt][bs0    ][brow][0] = cvt8(r1[0], r1[1]);
            *(s16x8*)&B1s[nxt][bs0 + 1][brow][0] = cvt8(r1[2], r1[3]);
            *(s16x8*)&B3s[nxt][bs0    ][brow][0] = cvt8(r3[0], r3[1]);
            *(s16x8*)&B3s[nxt][bs0 + 1][brow][0] = cvt8(r3[2], r3[3]);
        }
        __syncthreads();
    }

    // epilogue: SwiGLU + bf16 store
    int lc = lane & 15;
    int lr4 = (lane >> 4) * 4;
#pragma unroll
    for (int fm = 0; fm < 4; ++fm) {
#pragma unroll
        for (int r = 0; r < 4; ++r) {
            int row = wm + fm * 16 + lr4 + r;
            if (m0 + row < n_e) {
                size_t base = (size_t)(off + m0 + row) * ID + n0 + wn;
#pragma unroll
                for (int fn = 0; fn < 4; ++fn) {
                    float g = accg[fm][fn][r];
                    float u = accu[fm][fn][r];
                    float hv = g * u / (1.f + expf(-g));   // silu(g)*u
                    hbuf[base + fn * 16 + lc] = f2bf(hv);
                }
            }
        }
    }
}

// ---------------- K6: GEMM2 h @ w2^T -> per-slot fp32 ----------------
// 128x64 tile, 2 waves (each 64x64), same pipelined k-slab structure. 512 active blocks.
__global__ __launch_bounds__(128, 2)
void gemm2_kernel(const u16* __restrict__ hbuf, const float* __restrict__ w2,
                  const int* __restrict__ counts, const int* __restrict__ offsets,
                  float* __restrict__ out2) {
    const int NT = HD / 64;       // 16
    const int MT = NTOK / 128;    // 16
    int bid = blockIdx.x;
    int e = bid / (MT * NT);
    int rem = bid - e * (MT * NT);
    int mt = rem / NT;
    int nt = rem - mt * NT;
    int n_e = counts[e];
    int m0 = mt * 128;
    if (m0 >= n_e) return;
    int off = offsets[e];
    int n0 = nt * 64;

    __shared__ u16 As[2][4][128][8];   // 16 KB
    __shared__ u16 Bs[2][4][64][8];    //  8 KB

    int tid = threadIdx.x;
    int lane = tid & 63;
    int wid = tid >> 6;   // 0..1

    // A staging (glds): wave wid fills slabs {2wid, 2wid+1}, rows {lane, 64+lane}
    const u16* srcA0 = hbuf + (size_t)(off + m0 + lane) * ID + 2 * wid * 8;
    const u16* srcA1 = hbuf + (size_t)(off + m0 + 64 + lane) * ID + 2 * wid * 8;

    int brow = tid >> 1;               // 0..63
    int bs0 = (tid & 1) * 2;
    const float* pB = w2 + ((size_t)e * HD + n0 + brow) * ID + (tid & 1) * 16;

    f32x4 acc[4][4] = {};
    int wm = wid * 64;
    int lr = lane & 15, k8 = lane >> 4;
    f32x4 rb[4];

    // prologue
    glds16(srcA0,     &As[0][2 * wid    ][0][0]);
    glds16(srcA0 + 8, &As[0][2 * wid + 1][0][0]);
    glds16(srcA1,     &As[0][2 * wid    ][64][0]);
    glds16(srcA1 + 8, &As[0][2 * wid + 1][64][0]);
#pragma unroll
    for (int j = 0; j < 4; ++j) rb[j] = *(const f32x4*)(pB + 4 * j);
    *(s16x8*)&Bs[0][bs0    ][brow][0] = cvt8(rb[0], rb[1]);
    *(s16x8*)&Bs[0][bs0 + 1][brow][0] = cvt8(rb[2], rb[3]);
    __syncthreads();

    const int NIT = ID / 32;  // 112
    for (int it = 0; it < NIT; ++it) {
        int cur = it & 1, nxt = cur ^ 1;
        bool more = (it + 1) < NIT;
        int kn = (it + 1) * 32;
        if (more) {
            glds16(srcA0 + kn,     &As[nxt][2 * wid    ][0][0]);
            glds16(srcA0 + kn + 8, &As[nxt][2 * wid + 1][0][0]);
            glds16(srcA1 + kn,     &As[nxt][2 * wid    ][64][0]);
            glds16(srcA1 + kn + 8, &As[nxt][2 * wid + 1][64][0]);
#pragma unroll
            for (int j = 0; j < 4; ++j) rb[j] = *(const f32x4*)(pB + kn + 4 * j);
        }
        s16x8 a[4], b[4];
#pragma unroll
        for (int f = 0; f < 4; ++f) {
            a[f] = *(const s16x8*)&As[cur][k8][wm + f * 16 + lr][0];
            b[f] = *(const s16x8*)&Bs[cur][k8][f * 16 + lr][0];
        }
#pragma unroll
        for (int fm = 0; fm < 4; ++fm)
#pragma unroll
            for (int fn = 0; fn < 4; ++fn)
                acc[fm][fn] = __builtin_amdgcn_mfma_f32_16x16x32_bf16(a[fm], b[fn], acc[fm][fn], 0, 0, 0);
        if (more) {
            *(s16x8*)&Bs[nxt][bs0    ][brow][0] = cvt8(rb[0], rb[1]);
            *(s16x8*)&Bs[nxt][bs0 + 1][brow][0] = cvt8(rb[2], rb[3]);
        }
        __syncthreads();
    }

    int lc = lane & 15;
    int lr4 = (lane >> 4) * 4;
#pragma unroll
    for (int fm = 0; fm < 4; ++fm) {
#pragma unroll
        for (int r = 0; r < 4; ++r) {
            int row = wm + fm * 16 + lr4 + r;
            if (m0 + row < n_e) {
                float* dst = out2 + (size_t)(off + m0 + row) * HD + n0;
#pragma unroll
                for (int fn = 0; fn < 4; ++fn)
                    dst[fn * 16 + lc] = acc[fm][fn][r];
            }
        }
    }
}

// ---------------- K7: weighted combine ----------------
__global__ void combine_kernel(const float* __restrict__ out2, const int* __restrict__ slot_of,
                               const float* __restrict__ topk_w, float* __restrict__ y) {
    int i = blockIdx.x * 256 + threadIdx.x;   // over NTOK*HD/4
    int t = i >> 8;           // HD/4 = 256 float4 per token
    int c = i & 255;
    int s0 = slot_of[2 * t], s1 = slot_of[2 * t + 1];
    float w0 = topk_w[2 * t], w1 = topk_w[2 * t + 1];
    f32x4 a = ((const f32x4*)(out2 + (size_t)s0 * HD))[c];
    f32x4 b = ((const f32x4*)(out2 + (size_t)s1 * HD))[c];
    f32x4 o;
#pragma unroll
    for (int j = 0; j < 4; ++j) o[j] = w0 * a[j] + w1 * b[j];
    ((f32x4*)(y + (size_t)t * HD))[c] = o;
}

extern "C" void kernel_launch(void* const* d_in, const int* in_sizes, int n_in,
                              void* d_out, int out_size, void* d_ws, size_t ws_size,
                              hipStream_t stream) {
    (void)in_sizes; (void)n_in; (void)out_size; (void)ws_size;
    const float* x  = (const float*)d_in[0];
    const float* wg = (const float*)d_in[1];
    const float* w1 = (const float*)d_in[2];
    const float* w3 = (const float*)d_in[3];
    const float* w2 = (const float*)d_in[4];
    float* y = (float*)d_out;

    char* ws = (char*)d_ws;
    int*   counts   = (int*)(ws + 0);       // 8 ints
    int*   counts2  = (int*)(ws + 32);      // 8 ints
    int*   offsets  = (int*)(ws + 64);      // 8 ints
    int*   topk_idx = (int*)(ws + 128);                        // 4096 ints
    float* topk_w   = (float*)(ws + 128 + (size_t)NSLOT * 4);  // 4096 floats
    int*   rows     = (int*)(ws + 128 + (size_t)NSLOT * 8);    // 4224 ints
    int*   slot_of  = (int*)(ws + 128 + (size_t)NSLOT * 8 + (size_t)NSLOT_ALLOC * 4);
    size_t off_xbf = 128 + (size_t)NSLOT * 12 + (size_t)NSLOT_ALLOC * 4;
    off_xbf = (off_xbf + 255) & ~(size_t)255;
    u16* xbf = (u16*)(ws + off_xbf);
    size_t off_h = off_xbf + (size_t)NTOK * HD * 2;
    u16* hbuf = (u16*)(ws + off_h);
    size_t off_o2 = off_h + (size_t)NSLOT_ALLOC * ID * 2;
    float* out2 = (float*)(ws + off_o2);

    init_kernel<<<1, 64, 0, stream>>>(counts);
    router_kernel<<<NTOK, 64, 0, stream>>>(x, wg, topk_idx, topk_w, counts);
    scan_kernel<<<1, 128, 0, stream>>>(counts, offsets, rows);
    assign_kernel<<<NSLOT / 256, 256, 0, stream>>>(topk_idx, offsets, counts2, rows, slot_of);
    cvt_x_kernel<<<(NTOK * HD / 4) / 256, 256, 0, stream>>>(x, xbf);
    gemm1_kernel<<<NEXP * (NTOK / 128) * (ID / 128), 256, 0, stream>>>(xbf, w1, w3, counts, offsets, rows, hbuf);
    gemm2_kernel<<<NEXP * (NTOK / 128) * (HD / 64), 128, 0, stream>>>(hbuf, w2, counts, offsets, out2);
    combine_kernel<<<(NTOK * HD / 4) / 256, 256, 0, stream>>>(out2, slot_of, topk_w, y);
}

// Round 3
// 379.352 us; speedup vs baseline: 1.7477x; 1.7477x over previous
//
#include <hip/hip_runtime.h>
#include <hip/hip_bf16.h>
#include <stdint.h>

#define NEXP 8
#define HD 1024
#define ID 3584
#define NTOK 2048
#define NSLOT 4096          // NTOK * TOPK
#define SLOT_PAD 128
#define NSLOT_ALLOC (NSLOT + SLOT_PAD)
#define WN (NEXP * ID * HD)   // elements per weight tensor = 29,360,128

typedef unsigned short u16;
typedef __attribute__((ext_vector_type(8))) short s16x8;
typedef __attribute__((ext_vector_type(4))) short s16x4;
typedef __attribute__((ext_vector_type(4))) float f32x4;

__device__ __forceinline__ u16 f2bf(float f) {
    __hip_bfloat16 h = __float2bfloat16(f);   // RNE
    union { __hip_bfloat16 h; u16 u; } v; v.h = h; return v.u;
}

__device__ __forceinline__ s16x8 cvt8(f32x4 a, f32x4 b) {
    s16x8 o;
    o[0]=(short)f2bf(a[0]); o[1]=(short)f2bf(a[1]); o[2]=(short)f2bf(a[2]); o[3]=(short)f2bf(a[3]);
    o[4]=(short)f2bf(b[0]); o[5]=(short)f2bf(b[1]); o[6]=(short)f2bf(b[2]); o[7]=(short)f2bf(b[3]);
    return o;
}

__device__ __forceinline__ void glds16(const void* g, void* l) {
    __builtin_amdgcn_global_load_lds((const __attribute__((address_space(1))) unsigned*)g,
                                     (__attribute__((address_space(3))) unsigned*)l, 16, 0, 0);
}

// ---------------- K0: zero counters ----------------
__global__ void init_kernel(int* __restrict__ counts) {
    if (threadIdx.x < 16) counts[threadIdx.x] = 0;   // counts[8] + counts2[8]
}

// ---------------- K1: router (fp32, exact top-2) ----------------
__global__ void router_kernel(const float* __restrict__ x, const float* __restrict__ wg,
                              int* __restrict__ topk_idx, float* __restrict__ topk_w,
                              int* __restrict__ counts) {
    int t = blockIdx.x;
    int lane = threadIdx.x;   // 64 threads = 1 wave
    const float* xr = x + (size_t)t * HD;
    float acc[NEXP];
#pragma unroll
    for (int e = 0; e < NEXP; ++e) acc[e] = 0.f;
#pragma unroll
    for (int i = 0; i < HD / 256; ++i) {
        int h = i * 256 + lane * 4;
        f32x4 xv = *(const f32x4*)(xr + h);
#pragma unroll
        for (int e = 0; e < NEXP; ++e) {
            f32x4 wv = *(const f32x4*)(wg + e * HD + h);
            acc[e] += xv[0]*wv[0] + xv[1]*wv[1] + xv[2]*wv[2] + xv[3]*wv[3];
        }
    }
#pragma unroll
    for (int e = 0; e < NEXP; ++e) {
#pragma unroll
        for (int s = 32; s > 0; s >>= 1) acc[e] += __shfl_xor(acc[e], s, 64);
    }
    if (lane == 0) {
        int b0 = 0; float l0 = acc[0];
#pragma unroll
        for (int e = 1; e < NEXP; ++e) if (acc[e] > l0) { l0 = acc[e]; b0 = e; }
        int b1 = (b0 == 0) ? 1 : 0; float l1 = acc[b1];
#pragma unroll
        for (int e = 0; e < NEXP; ++e) {
            if (e == b0 || e == b1) continue;
            if (acc[e] > l1) { l1 = acc[e]; b1 = e; }
        }
        float w0 = 1.f / (1.f + expf(l1 - l0));   // renormalized top-2 softmax
        float w1 = 1.f - w0;
        topk_idx[2 * t] = b0; topk_idx[2 * t + 1] = b1;
        topk_w[2 * t] = w0;  topk_w[2 * t + 1] = w1;
        atomicAdd(&counts[b0], 1);
        atomicAdd(&counts[b1], 1);
    }
}

// ---------------- K2: exclusive scan + pad rows ----------------
__global__ void scan_kernel(const int* __restrict__ counts, int* __restrict__ offsets,
                            int* __restrict__ rows) {
    if (threadIdx.x == 0) {
        int off = 0;
#pragma unroll
        for (int e = 0; e < NEXP; ++e) { offsets[e] = off; off += counts[e]; }
    }
    if (threadIdx.x < SLOT_PAD) rows[NSLOT + threadIdx.x] = 0;
}

// ---------------- K3: slot assignment ----------------
__global__ void assign_kernel(const int* __restrict__ topk_idx, const int* __restrict__ offsets,
                              int* __restrict__ counts2, int* __restrict__ rows,
                              int* __restrict__ slot_of) {
    int i = blockIdx.x * 256 + threadIdx.x;   // 0..4095
    int e = topk_idx[i];
    int pos = atomicAdd(&counts2[e], 1);
    int slot = offsets[e] + pos;
    rows[slot] = i >> 1;       // token id
    slot_of[i] = slot;
}

// ---------------- K4: generic fp32 -> bf16 (grid-stride over 8-elem units) ----------------
__global__ __launch_bounds__(256)
void cvt_bf_kernel(const float* __restrict__ src, u16* __restrict__ dst, int n8) {
    int stride = gridDim.x * 256;
    for (int i = blockIdx.x * 256 + threadIdx.x; i < n8; i += stride) {
        f32x4 v0 = ((const f32x4*)src)[2 * i];
        f32x4 v1 = ((const f32x4*)src)[2 * i + 1];
        ((s16x8*)dst)[i] = cvt8(v0, v1);
    }
}

// ---------------- K5: fused GEMM1 (g,u) + SwiGLU -> h (bf16) ----------------
// m97 structure: 128x128 tile, BK=32, linear [rows][32] bf16 LDS, glds-16 for A and B,
// single-buffered 2-barrier K-loop. Zero VALU in staging.
__global__ __launch_bounds__(256, 2)
void gemm1_kernel(const u16* __restrict__ xbf, const u16* __restrict__ w1bf,
                  const u16* __restrict__ w3bf, const int* __restrict__ counts,
                  const int* __restrict__ offsets, const int* __restrict__ rows,
                  u16* __restrict__ hbuf) {
    const int NT = ID / 128;      // 28
    const int MT = NTOK / 128;    // 16
    int bid = blockIdx.x;
    int e = bid / (MT * NT);
    int rem = bid - e * (MT * NT);
    int mt = rem / NT;
    int nt = rem - mt * NT;
    int n_e = counts[e];
    int m0 = mt * 128;
    if (m0 >= n_e) return;
    int off = offsets[e];
    int n0 = nt * 128;

    __shared__ u16 As[128][32];    // 8 KB
    __shared__ u16 B1s[128][32];   // 8 KB
    __shared__ u16 B3s[128][32];   // 8 KB

    int tid = threadIdx.x;
    int lane = tid & 63;
    int wid = tid >> 6;

    // wave `wid` stages rows [32*wid, 32*wid+32) of each tile; 4 lanes per row, 16B chunks
    int srow = wid * 32 + (lane >> 2);     // rows srow (first glds), srow+16 (second)
    int chunk = (lane & 3) * 8;            // k-elem offset of this lane's 16B

    int tokA0 = rows[off + m0 + srow];
    int tokA1 = rows[off + m0 + srow + 16];
    const u16* srcA0 = xbf + (size_t)tokA0 * HD + chunk;
    const u16* srcA1 = xbf + (size_t)tokA1 * HD + chunk;
    const u16* srcB1a = w1bf + ((size_t)e * ID + n0 + srow) * HD + chunk;
    const u16* srcB1b = srcB1a + (size_t)16 * HD;
    const u16* srcB3a = w3bf + ((size_t)e * ID + n0 + srow) * HD + chunk;
    const u16* srcB3b = srcB3a + (size_t)16 * HD;

    f32x4 accg[4][4] = {}, accu[4][4] = {};
    int wm = (wid >> 1) * 64, wn = (wid & 1) * 64;
    int lr = lane & 15, k8 = (lane >> 4) * 8;

    for (int k0 = 0; k0 < HD; k0 += 32) {
        glds16(srcA0 + k0, &As[wid * 32][0]);
        glds16(srcA1 + k0, &As[wid * 32 + 16][0]);
        glds16(srcB1a + k0, &B1s[wid * 32][0]);
        glds16(srcB1b + k0, &B1s[wid * 32 + 16][0]);
        glds16(srcB3a + k0, &B3s[wid * 32][0]);
        glds16(srcB3b + k0, &B3s[wid * 32 + 16][0]);
        __syncthreads();
        s16x8 a[4], b1[4], b3[4];
#pragma unroll
        for (int f = 0; f < 4; ++f) {
            a[f]  = *(const s16x8*)&As[wm + f * 16 + lr][k8];
            b1[f] = *(const s16x8*)&B1s[wn + f * 16 + lr][k8];
            b3[f] = *(const s16x8*)&B3s[wn + f * 16 + lr][k8];
        }
#pragma unroll
        for (int fm = 0; fm < 4; ++fm)
#pragma unroll
            for (int fn = 0; fn < 4; ++fn) {
                accg[fm][fn] = __builtin_amdgcn_mfma_f32_16x16x32_bf16(a[fm], b1[fn], accg[fm][fn], 0, 0, 0);
                accu[fm][fn] = __builtin_amdgcn_mfma_f32_16x16x32_bf16(a[fm], b3[fn], accu[fm][fn], 0, 0, 0);
            }
        __syncthreads();
    }

    // epilogue: SwiGLU + bf16 store
    int lc = lane & 15;
    int lr4 = (lane >> 4) * 4;
#pragma unroll
    for (int fm = 0; fm < 4; ++fm) {
#pragma unroll
        for (int r = 0; r < 4; ++r) {
            int row = wm + fm * 16 + lr4 + r;
            if (m0 + row < n_e) {
                size_t base = (size_t)(off + m0 + row) * ID + n0 + wn;
#pragma unroll
                for (int fn = 0; fn < 4; ++fn) {
                    float g = accg[fm][fn][r];
                    float u = accu[fm][fn][r];
                    float hv = g * u / (1.f + expf(-g));   // silu(g)*u
                    hbuf[base + fn * 16 + lc] = f2bf(hv);
                }
            }
        }
    }
}

// ---------------- K6: GEMM2 h @ w2bf^T -> per-slot fp32, split-K x2 ----------------
#define KSPLIT 2
#define KLEN (ID / KSPLIT)   // 1792
__global__ __launch_bounds__(256, 3)
void gemm2_kernel(const u16* __restrict__ hbuf, const u16* __restrict__ w2bf,
                  const int* __restrict__ counts, const int* __restrict__ offsets,
                  float* __restrict__ out2) {
    const int NT = HD / 128;      // 8
    const int MT = NTOK / 128;    // 16
    int bid = blockIdx.x;
    int e = bid / (MT * NT * KSPLIT);
    int rem = bid - e * (MT * NT * KSPLIT);
    int mt = rem / (NT * KSPLIT);
    int rem2 = rem - mt * (NT * KSPLIT);
    int nt = rem2 / KSPLIT;
    int ks = rem2 - nt * KSPLIT;
    int n_e = counts[e];
    int m0 = mt * 128;
    if (m0 >= n_e) return;
    int off = offsets[e];
    int n0 = nt * 128;
    int kbase = ks * KLEN;

    __shared__ u16 As[128][32];   // 8 KB
    __shared__ u16 Bs[128][32];   // 8 KB

    int tid = threadIdx.x;
    int lane = tid & 63;
    int wid = tid >> 6;

    int srow = wid * 32 + (lane >> 2);
    int chunk = (lane & 3) * 8;
    const u16* srcA0 = hbuf + (size_t)(off + m0 + srow) * ID + kbase + chunk;
    const u16* srcA1 = srcA0 + (size_t)16 * ID;
    const u16* srcB0 = w2bf + ((size_t)e * HD + n0 + srow) * ID + kbase + chunk;
    const u16* srcB1 = srcB0 + (size_t)16 * ID;

    f32x4 acc[4][4] = {};
    int wm = (wid >> 1) * 64, wn = (wid & 1) * 64;
    int lr = lane & 15, k8 = (lane >> 4) * 8;

    for (int k0 = 0; k0 < KLEN; k0 += 32) {
        glds16(srcA0 + k0, &As[wid * 32][0]);
        glds16(srcA1 + k0, &As[wid * 32 + 16][0]);
        glds16(srcB0 + k0, &Bs[wid * 32][0]);
        glds16(srcB1 + k0, &Bs[wid * 32 + 16][0]);
        __syncthreads();
        s16x8 a[4], b[4];
#pragma unroll
        for (int f = 0; f < 4; ++f) {
            a[f] = *(const s16x8*)&As[wm + f * 16 + lr][k8];
            b[f] = *(const s16x8*)&Bs[wn + f * 16 + lr][k8];
        }
#pragma unroll
        for (int fm = 0; fm < 4; ++fm)
#pragma unroll
            for (int fn = 0; fn < 4; ++fn)
                acc[fm][fn] = __builtin_amdgcn_mfma_f32_16x16x32_bf16(a[fm], b[fn], acc[fm][fn], 0, 0, 0);
        __syncthreads();
    }

    float* outp = out2 + (size_t)ks * NSLOT_ALLOC * HD;
    int lc = lane & 15;
    int lr4 = (lane >> 4) * 4;
#pragma unroll
    for (int fm = 0; fm < 4; ++fm) {
#pragma unroll
        for (int r = 0; r < 4; ++r) {
            int row = wm + fm * 16 + lr4 + r;
            if (m0 + row < n_e) {
                float* dst = outp + (size_t)(off + m0 + row) * HD + n0 + wn;
#pragma unroll
                for (int fn = 0; fn < 4; ++fn)
                    dst[fn * 16 + lc] = acc[fm][fn][r];
            }
        }
    }
}

// ---------------- K7: weighted combine (sums split-K partials) ----------------
__global__ void combine_kernel(const float* __restrict__ out2, const int* __restrict__ slot_of,
                               const float* __restrict__ topk_w, float* __restrict__ y) {
    int i = blockIdx.x * 256 + threadIdx.x;   // over NTOK*HD/4
    int t = i >> 8;           // HD/4 = 256 float4 per token
    int c = i & 255;
    int s0 = slot_of[2 * t], s1 = slot_of[2 * t + 1];
    float w0 = topk_w[2 * t], w1 = topk_w[2 * t + 1];
    const float* p0 = out2;
    const float* p1 = out2 + (size_t)NSLOT_ALLOC * HD;
    f32x4 a0 = ((const f32x4*)(p0 + (size_t)s0 * HD))[c];
    f32x4 a1 = ((const f32x4*)(p1 + (size_t)s0 * HD))[c];
    f32x4 b0 = ((const f32x4*)(p0 + (size_t)s1 * HD))[c];
    f32x4 b1 = ((const f32x4*)(p1 + (size_t)s1 * HD))[c];
    f32x4 o;
#pragma unroll
    for (int j = 0; j < 4; ++j) o[j] = w0 * (a0[j] + a1[j]) + w1 * (b0[j] + b1[j]);
    ((f32x4*)(y + (size_t)t * HD))[c] = o;
}

extern "C" void kernel_launch(void* const* d_in, const int* in_sizes, int n_in,
                              void* d_out, int out_size, void* d_ws, size_t ws_size,
                              hipStream_t stream) {
    (void)in_sizes; (void)n_in; (void)out_size; (void)ws_size;
    const float* x  = (const float*)d_in[0];
    const float* wg = (const float*)d_in[1];
    const float* w1 = (const float*)d_in[2];
    const float* w3 = (const float*)d_in[3];
    const float* w2 = (const float*)d_in[4];
    float* y = (float*)d_out;

    char* ws = (char*)d_ws;
    int*   counts   = (int*)(ws + 0);       // 8 ints
    int*   counts2  = (int*)(ws + 32);      // 8 ints
    int*   offsets  = (int*)(ws + 64);      // 8 ints
    int*   topk_idx = (int*)(ws + 128);                        // 4096 ints
    float* topk_w   = (float*)(ws + 128 + (size_t)NSLOT * 4);  // 4096 floats
    int*   rows     = (int*)(ws + 128 + (size_t)NSLOT * 8);    // 4224 ints
    int*   slot_of  = (int*)(ws + 128 + (size_t)NSLOT * 8 + (size_t)NSLOT_ALLOC * 4);
    size_t off_xbf = 128 + (size_t)NSLOT * 12 + (size_t)NSLOT_ALLOC * 4;
    off_xbf = (off_xbf + 255) & ~(size_t)255;
    u16* xbf = (u16*)(ws + off_xbf);
    size_t off_h = off_xbf + (size_t)NTOK * HD * 2;
    u16* hbuf = (u16*)(ws + off_h);
    size_t off_w1 = off_h + (size_t)NSLOT_ALLOC * ID * 2;
    u16* w1bf = (u16*)(ws + off_w1);
    size_t off_w3 = off_w1 + (size_t)WN * 2;
    u16* w3bf = (u16*)(ws + off_w3);
    size_t off_w2 = off_w3 + (size_t)WN * 2;
    u16* w2bf = (u16*)(ws + off_w2);
    size_t off_o2 = off_w2 + (size_t)WN * 2;
    float* out2 = (float*)(ws + off_o2);    // KSPLIT partial buffers

    init_kernel<<<1, 64, 0, stream>>>(counts);
    router_kernel<<<NTOK, 64, 0, stream>>>(x, wg, topk_idx, topk_w, counts);
    scan_kernel<<<1, 128, 0, stream>>>(counts, offsets, rows);
    assign_kernel<<<NSLOT / 256, 256, 0, stream>>>(topk_idx, offsets, counts2, rows, slot_of);
    cvt_bf_kernel<<<2048, 256, 0, stream>>>(x, xbf, NTOK * HD / 8);
    cvt_bf_kernel<<<2048, 256, 0, stream>>>(w1, w1bf, WN / 8);
    cvt_bf_kernel<<<2048, 256, 0, stream>>>(w3, w3bf, WN / 8);
    cvt_bf_kernel<<<2048, 256, 0, stream>>>(w2, w2bf, WN / 8);
    gemm1_kernel<<<NEXP * (NTOK / 128) * (ID / 128), 256, 0, stream>>>(xbf, w1bf, w3bf, counts, offsets, rows, hbuf);
    gemm2_kernel<<<NEXP * (NTOK / 128) * (HD / 128) * KSPLIT, 256, 0, stream>>>(hbuf, w2bf, counts, offsets, out2);
    combine_kernel<<<(NTOK * HD / 4) / 256, 256, 0, stream>>>(out2, slot_of, topk_w, y);
}

// Round 4
// 360.594 us; speedup vs baseline: 1.8386x; 1.0520x over previous
//
#include <hip/hip_runtime.h>
#include <hip/hip_bf16.h>
#include <stdint.h>

#define NEXP 8
#define HD 1024
#define ID 3584
#define NTOK 2048
#define NSLOT 4096          // NTOK * TOPK
#define SLOT_PAD 128
#define NSLOT_ALLOC (NSLOT + SLOT_PAD)
#define WN (NEXP * ID * HD)   // elements per weight tensor = 29,360,128
#define KSPLIT 4
#define KLEN (ID / KSPLIT)    // 896

typedef unsigned short u16;
typedef __attribute__((ext_vector_type(8))) short s16x8;
typedef __attribute__((ext_vector_type(4))) short s16x4;
typedef __attribute__((ext_vector_type(4))) float f32x4;

__device__ __forceinline__ u16 f2bf(float f) {
    __hip_bfloat16 h = __float2bfloat16(f);   // RNE
    union { __hip_bfloat16 h; u16 u; } v; v.h = h; return v.u;
}

__device__ __forceinline__ s16x8 cvt8(f32x4 a, f32x4 b) {
    s16x8 o;
    o[0]=(short)f2bf(a[0]); o[1]=(short)f2bf(a[1]); o[2]=(short)f2bf(a[2]); o[3]=(short)f2bf(a[3]);
    o[4]=(short)f2bf(b[0]); o[5]=(short)f2bf(b[1]); o[6]=(short)f2bf(b[2]); o[7]=(short)f2bf(b[3]);
    return o;
}

__device__ __forceinline__ void glds16(const void* g, void* l) {
    __builtin_amdgcn_global_load_lds((const __attribute__((address_space(1))) unsigned*)g,
                                     (__attribute__((address_space(3))) unsigned*)l, 16, 0, 0);
}

// ---------------- K0: zero counters ----------------
__global__ void init_kernel(int* __restrict__ counts) {
    if (threadIdx.x < 16) counts[threadIdx.x] = 0;   // counts[8] + counts2[8]
}

// ---------------- K1: router (fp32, exact top-2) ----------------
__global__ void router_kernel(const float* __restrict__ x, const float* __restrict__ wg,
                              int* __restrict__ topk_idx, float* __restrict__ topk_w,
                              int* __restrict__ counts) {
    int t = blockIdx.x;
    int lane = threadIdx.x;   // 64 threads = 1 wave
    const float* xr = x + (size_t)t * HD;
    float acc[NEXP];
#pragma unroll
    for (int e = 0; e < NEXP; ++e) acc[e] = 0.f;
#pragma unroll
    for (int i = 0; i < HD / 256; ++i) {
        int h = i * 256 + lane * 4;
        f32x4 xv = *(const f32x4*)(xr + h);
#pragma unroll
        for (int e = 0; e < NEXP; ++e) {
            f32x4 wv = *(const f32x4*)(wg + e * HD + h);
            acc[e] += xv[0]*wv[0] + xv[1]*wv[1] + xv[2]*wv[2] + xv[3]*wv[3];
        }
    }
#pragma unroll
    for (int e = 0; e < NEXP; ++e) {
#pragma unroll
        for (int s = 32; s > 0; s >>= 1) acc[e] += __shfl_xor(acc[e], s, 64);
    }
    if (lane == 0) {
        int b0 = 0; float l0 = acc[0];
#pragma unroll
        for (int e = 1; e < NEXP; ++e) if (acc[e] > l0) { l0 = acc[e]; b0 = e; }
        int b1 = (b0 == 0) ? 1 : 0; float l1 = acc[b1];
#pragma unroll
        for (int e = 0; e < NEXP; ++e) {
            if (e == b0 || e == b1) continue;
            if (acc[e] > l1) { l1 = acc[e]; b1 = e; }
        }
        float w0 = 1.f / (1.f + expf(l1 - l0));   // renormalized top-2 softmax
        float w1 = 1.f - w0;
        topk_idx[2 * t] = b0; topk_idx[2 * t + 1] = b1;
        topk_w[2 * t] = w0;  topk_w[2 * t + 1] = w1;
        atomicAdd(&counts[b0], 1);
        atomicAdd(&counts[b1], 1);
    }
}

// ---------------- K2: exclusive scan + pad rows ----------------
__global__ void scan_kernel(const int* __restrict__ counts, int* __restrict__ offsets,
                            int* __restrict__ rows) {
    if (threadIdx.x == 0) {
        int off = 0;
#pragma unroll
        for (int e = 0; e < NEXP; ++e) { offsets[e] = off; off += counts[e]; }
    }
    if (threadIdx.x < SLOT_PAD) rows[NSLOT + threadIdx.x] = 0;
}

// ---------------- K3: slot assignment ----------------
__global__ void assign_kernel(const int* __restrict__ topk_idx, const int* __restrict__ offsets,
                              int* __restrict__ counts2, int* __restrict__ rows,
                              int* __restrict__ slot_of) {
    int i = blockIdx.x * 256 + threadIdx.x;   // 0..4095
    int e = topk_idx[i];
    int pos = atomicAdd(&counts2[e], 1);
    int slot = offsets[e] + pos;
    rows[slot] = i >> 1;       // token id
    slot_of[i] = slot;
}

// ---------------- K4: generic fp32 -> bf16 (grid-stride over 8-elem units) ----------------
__global__ __launch_bounds__(256)
void cvt_bf_kernel(const float* __restrict__ src, u16* __restrict__ dst, int n8) {
    int stride = gridDim.x * 256;
    for (int i = blockIdx.x * 256 + threadIdx.x; i < n8; i += stride) {
        f32x4 v0 = ((const f32x4*)src)[2 * i];
        f32x4 v1 = ((const f32x4*)src)[2 * i + 1];
        ((s16x8*)dst)[i] = cvt8(v0, v1);
    }
}

// ---------------- K5: FAT kernel: fused GEMM1 (g,u)+SwiGLU -> h  ||  w2 fp32->bf16 ----------------
// GEMM1: 128x128 dual-B tile, BK=32, double-buffered prefetch pipeline (stage next
// BEFORE compute; single barrier/step drains in-flight loads after compute covered them).
#define G1_BLOCKS (NEXP * (NTOK / 128) * (ID / 128))   // 3584
#define CVT2_BLOCKS 1024
__global__ __launch_bounds__(256, 2)
void gemm1_kernel(const u16* __restrict__ xbf, const u16* __restrict__ w1bf,
                  const u16* __restrict__ w3bf, const int* __restrict__ counts,
                  const int* __restrict__ offsets, const int* __restrict__ rows,
                  u16* __restrict__ hbuf,
                  const float* __restrict__ w2, u16* __restrict__ w2bf) {
    __shared__ u16 As[2][128][32];    // 16 KB
    __shared__ u16 B1s[2][128][32];   // 16 KB
    __shared__ u16 B3s[2][128][32];   // 16 KB

    if (blockIdx.x >= G1_BLOCKS) {
        // ---- side job: convert w2 to bf16 (overlaps with GEMM1 blocks) ----
        const int stride = CVT2_BLOCKS * 256;
        for (int i = (blockIdx.x - G1_BLOCKS) * 256 + threadIdx.x; i < WN / 8; i += stride) {
            f32x4 v0 = ((const f32x4*)w2)[2 * i];
            f32x4 v1 = ((const f32x4*)w2)[2 * i + 1];
            ((s16x8*)w2bf)[i] = cvt8(v0, v1);
        }
        return;
    }

    const int NT = ID / 128;      // 28
    int bid = blockIdx.x;
    int e = bid / (16 * NT);
    int rem = bid - e * (16 * NT);
    int mt = rem / NT;
    int nt = rem - mt * NT;
    int n_e = counts[e];
    int m0 = mt * 128;
    if (m0 >= n_e) return;
    int off = offsets[e];
    int n0 = nt * 128;

    int tid = threadIdx.x;
    int lane = tid & 63;
    int wid = tid >> 6;

    // wave `wid` stages rows [32*wid, 32*wid+32): 4 lanes/row, 16B chunks, linear order
    int srow = wid * 32 + (lane >> 2);
    int chunk = (lane & 3) * 8;

    int tokA0 = rows[off + m0 + srow];
    int tokA1 = rows[off + m0 + srow + 16];
    const u16* srcA0 = xbf + (size_t)tokA0 * HD + chunk;
    const u16* srcA1 = xbf + (size_t)tokA1 * HD + chunk;
    const u16* srcB1a = w1bf + ((size_t)e * ID + n0 + srow) * HD + chunk;
    const u16* srcB1b = srcB1a + (size_t)16 * HD;
    const u16* srcB3a = w3bf + ((size_t)e * ID + n0 + srow) * HD + chunk;
    const u16* srcB3b = srcB3a + (size_t)16 * HD;

    f32x4 accg[4][4] = {}, accu[4][4] = {};
    int wm = (wid >> 1) * 64, wn = (wid & 1) * 64;
    int lr = lane & 15, k8 = (lane >> 4) * 8;

#define STAGE1(b, k0)                                      \
    do {                                                   \
        glds16(srcA0 + (k0),  &As[b][wid * 32][0]);        \
        glds16(srcA1 + (k0),  &As[b][wid * 32 + 16][0]);   \
        glds16(srcB1a + (k0), &B1s[b][wid * 32][0]);       \
        glds16(srcB1b + (k0), &B1s[b][wid * 32 + 16][0]);  \
        glds16(srcB3a + (k0), &B3s[b][wid * 32][0]);       \
        glds16(srcB3b + (k0), &B3s[b][wid * 32 + 16][0]);  \
    } while (0)

    STAGE1(0, 0);
    __syncthreads();

    const int NIT = HD / 32;  // 32
    for (int it = 0; it < NIT; ++it) {
        int cur = it & 1;
        if (it + 1 < NIT) STAGE1(cur ^ 1, (it + 1) * 32);   // prefetch: flies during MFMA
        s16x8 a[4], b1[4], b3[4];
#pragma unroll
        for (int f = 0; f < 4; ++f) {
            a[f]  = *(const s16x8*)&As[cur][wm + f * 16 + lr][k8];
            b1[f] = *(const s16x8*)&B1s[cur][wn + f * 16 + lr][k8];
            b3[f] = *(const s16x8*)&B3s[cur][wn + f * 16 + lr][k8];
        }
#pragma unroll
        for (int fm = 0; fm < 4; ++fm)
#pragma unroll
            for (int fn = 0; fn < 4; ++fn) {
                accg[fm][fn] = __builtin_amdgcn_mfma_f32_16x16x32_bf16(a[fm], b1[fn], accg[fm][fn], 0, 0, 0);
                accu[fm][fn] = __builtin_amdgcn_mfma_f32_16x16x32_bf16(a[fm], b3[fn], accu[fm][fn], 0, 0, 0);
            }
        __syncthreads();   // drains the prefetch (already covered) + publishes buffers
    }

    // epilogue: SwiGLU + bf16 store
    int lc = lane & 15;
    int lr4 = (lane >> 4) * 4;
#pragma unroll
    for (int fm = 0; fm < 4; ++fm) {
#pragma unroll
        for (int r = 0; r < 4; ++r) {
            int row = wm + fm * 16 + lr4 + r;
            if (m0 + row < n_e) {
                size_t base = (size_t)(off + m0 + row) * ID + n0 + wn;
#pragma unroll
                for (int fn = 0; fn < 4; ++fn) {
                    float g = accg[fm][fn][r];
                    float u = accu[fm][fn][r];
                    float hv = g * u / (1.f + expf(-g));   // silu(g)*u
                    hbuf[base + fn * 16 + lc] = f2bf(hv);
                }
            }
        }
    }
}

// ---------------- K6: GEMM2 h @ w2bf^T -> per-slot fp32, split-K x4, pipelined ----------------
__global__ __launch_bounds__(256, 2)
void gemm2_kernel(const u16* __restrict__ hbuf, const u16* __restrict__ w2bf,
                  const int* __restrict__ counts, const int* __restrict__ offsets,
                  float* __restrict__ out2) {
    const int NT = HD / 128;      // 8
    int bid = blockIdx.x;
    int e = bid / (16 * NT * KSPLIT);
    int rem = bid - e * (16 * NT * KSPLIT);
    int mt = rem / (NT * KSPLIT);
    int rem2 = rem - mt * (NT * KSPLIT);
    int nt = rem2 / KSPLIT;
    int ks = rem2 - nt * KSPLIT;
    int n_e = counts[e];
    int m0 = mt * 128;
    if (m0 >= n_e) return;
    int off = offsets[e];
    int n0 = nt * 128;
    int kbase = ks * KLEN;

    __shared__ u16 As[2][128][32];   // 16 KB
    __shared__ u16 Bs[2][128][32];   // 16 KB

    int tid = threadIdx.x;
    int lane = tid & 63;
    int wid = tid >> 6;

    int srow = wid * 32 + (lane >> 2);
    int chunk = (lane & 3) * 8;
    const u16* srcA0 = hbuf + (size_t)(off + m0 + srow) * ID + kbase + chunk;
    const u16* srcA1 = srcA0 + (size_t)16 * ID;
    const u16* srcB0 = w2bf + ((size_t)e * HD + n0 + srow) * ID + kbase + chunk;
    const u16* srcB1 = srcB0 + (size_t)16 * ID;

    f32x4 acc[4][4] = {};
    int wm = (wid >> 1) * 64, wn = (wid & 1) * 64;
    int lr = lane & 15, k8 = (lane >> 4) * 8;

#define STAGE2(b, k0)                                    \
    do {                                                 \
        glds16(srcA0 + (k0), &As[b][wid * 32][0]);       \
        glds16(srcA1 + (k0), &As[b][wid * 32 + 16][0]);  \
        glds16(srcB0 + (k0), &Bs[b][wid * 32][0]);       \
        glds16(srcB1 + (k0), &Bs[b][wid * 32 + 16][0]);  \
    } while (0)

    STAGE2(0, 0);
    __syncthreads();

    const int NIT = KLEN / 32;  // 28
    for (int it = 0; it < NIT; ++it) {
        int cur = it & 1;
        if (it + 1 < NIT) STAGE2(cur ^ 1, (it + 1) * 32);
        s16x8 a[4], b[4];
#pragma unroll
        for (int f = 0; f < 4; ++f) {
            a[f] = *(const s16x8*)&As[cur][wm + f * 16 + lr][k8];
            b[f] = *(const s16x8*)&Bs[cur][wn + f * 16 + lr][k8];
        }
#pragma unroll
        for (int fm = 0; fm < 4; ++fm)
#pragma unroll
            for (int fn = 0; fn < 4; ++fn)
                acc[fm][fn] = __builtin_amdgcn_mfma_f32_16x16x32_bf16(a[fm], b[fn], acc[fm][fn], 0, 0, 0);
        __syncthreads();
    }

    float* outp = out2 + (size_t)ks * NSLOT_ALLOC * HD;
    int lc = lane & 15;
    int lr4 = (lane >> 4) * 4;
#pragma unroll
    for (int fm = 0; fm < 4; ++fm) {
#pragma unroll
        for (int r = 0; r < 4; ++r) {
            int row = wm + fm * 16 + lr4 + r;
            if (m0 + row < n_e) {
                float* dst = outp + (size_t)(off + m0 + row) * HD + n0 + wn;
#pragma unroll
                for (int fn = 0; fn < 4; ++fn)
                    dst[fn * 16 + lc] = acc[fm][fn][r];
            }
        }
    }
}

// ---------------- K7: weighted combine (sums KSPLIT partials) ----------------
__global__ void combine_kernel(const float* __restrict__ out2, const int* __restrict__ slot_of,
                               const float* __restrict__ topk_w, float* __restrict__ y) {
    int i = blockIdx.x * 256 + threadIdx.x;   // over NTOK*HD/4
    int t = i >> 8;           // HD/4 = 256 float4 per token
    int c = i & 255;
    int s0 = slot_of[2 * t], s1 = slot_of[2 * t + 1];
    float w0 = topk_w[2 * t], w1 = topk_w[2 * t + 1];
    f32x4 o = {0.f, 0.f, 0.f, 0.f};
#pragma unroll
    for (int ks = 0; ks < KSPLIT; ++ks) {
        const float* p = out2 + (size_t)ks * NSLOT_ALLOC * HD;
        f32x4 a = ((const f32x4*)(p + (size_t)s0 * HD))[c];
        f32x4 b = ((const f32x4*)(p + (size_t)s1 * HD))[c];
#pragma unroll
        for (int j = 0; j < 4; ++j) o[j] += w0 * a[j] + w1 * b[j];
    }
    ((f32x4*)(y + (size_t)t * HD))[c] = o;
}

extern "C" void kernel_launch(void* const* d_in, const int* in_sizes, int n_in,
                              void* d_out, int out_size, void* d_ws, size_t ws_size,
                              hipStream_t stream) {
    (void)in_sizes; (void)n_in; (void)out_size; (void)ws_size;
    const float* x  = (const float*)d_in[0];
    const float* wg = (const float*)d_in[1];
    const float* w1 = (const float*)d_in[2];
    const float* w3 = (const float*)d_in[3];
    const float* w2 = (const float*)d_in[4];
    float* y = (float*)d_out;

    char* ws = (char*)d_ws;
    int*   counts   = (int*)(ws + 0);       // 8 ints
    int*   counts2  = (int*)(ws + 32);      // 8 ints
    int*   offsets  = (int*)(ws + 64);      // 8 ints
    int*   topk_idx = (int*)(ws + 128);                        // 4096 ints
    float* topk_w   = (float*)(ws + 128 + (size_t)NSLOT * 4);  // 4096 floats
    int*   rows     = (int*)(ws + 128 + (size_t)NSLOT * 8);    // 4224 ints
    int*   slot_of  = (int*)(ws + 128 + (size_t)NSLOT * 8 + (size_t)NSLOT_ALLOC * 4);
    size_t off_xbf = 128 + (size_t)NSLOT * 12 + (size_t)NSLOT_ALLOC * 4;
    off_xbf = (off_xbf + 255) & ~(size_t)255;
    u16* xbf = (u16*)(ws + off_xbf);
    size_t off_h = off_xbf + (size_t)NTOK * HD * 2;
    u16* hbuf = (u16*)(ws + off_h);
    size_t off_w1 = off_h + (size_t)NSLOT_ALLOC * ID * 2;
    u16* w1bf = (u16*)(ws + off_w1);
    size_t off_w3 = off_w1 + (size_t)WN * 2;
    u16* w3bf = (u16*)(ws + off_w3);
    size_t off_w2 = off_w3 + (size_t)WN * 2;
    u16* w2bf = (u16*)(ws + off_w2);
    size_t off_o2 = off_w2 + (size_t)WN * 2;
    float* out2 = (float*)(ws + off_o2);    // KSPLIT partial buffers

    init_kernel<<<1, 64, 0, stream>>>(counts);
    router_kernel<<<NTOK, 64, 0, stream>>>(x, wg, topk_idx, topk_w, counts);
    scan_kernel<<<1, 128, 0, stream>>>(counts, offsets, rows);
    assign_kernel<<<NSLOT / 256, 256, 0, stream>>>(topk_idx, offsets, counts2, rows, slot_of);
    cvt_bf_kernel<<<2048, 256, 0, stream>>>(x, xbf, NTOK * HD / 8);
    cvt_bf_kernel<<<2048, 256, 0, stream>>>(w1, w1bf, WN / 8);
    cvt_bf_kernel<<<2048, 256, 0, stream>>>(w3, w3bf, WN / 8);
    gemm1_kernel<<<G1_BLOCKS + CVT2_BLOCKS, 256, 0, stream>>>(xbf, w1bf, w3bf, counts, offsets, rows, hbuf, w2, w2bf);
    gemm2_kernel<<<NEXP * (NTOK / 128) * (HD / 128) * KSPLIT, 256, 0, stream>>>(hbuf, w2bf, counts, offsets, out2);
    combine_kernel<<<(NTOK * HD / 4) / 256, 256, 0, stream>>>(out2, slot_of, topk_w, y);
}

// Round 6
// 342.037 us; speedup vs baseline: 1.9384x; 1.0543x over previous
//
#include <hip/hip_runtime.h>
#include <hip/hip_bf16.h>
#include <stdint.h>

#define NEXP 8
#define HD 1024
#define ID 3584
#define NTOK 2048
#define NSLOT 4096          // NTOK * TOPK
#define SLOT_PAD 128
#define NSLOT_ALLOC (NSLOT + SLOT_PAD)
#define WN (NEXP * ID * HD)   // elements per weight tensor = 29,360,128
#define KSPLIT 4
#define KLEN (ID / KSPLIT)    // 896

typedef unsigned short u16;
typedef __attribute__((ext_vector_type(8))) short s16x8;
typedef __attribute__((ext_vector_type(4))) short s16x4;
typedef __attribute__((ext_vector_type(4))) float f32x4;

__device__ __forceinline__ u16 f2bf(float f) {
    __hip_bfloat16 h = __float2bfloat16(f);   // RNE
    union { __hip_bfloat16 h; u16 u; } v; v.h = h; return v.u;
}

__device__ __forceinline__ s16x8 cvt8(f32x4 a, f32x4 b) {
    s16x8 o;
    o[0]=(short)f2bf(a[0]); o[1]=(short)f2bf(a[1]); o[2]=(short)f2bf(a[2]); o[3]=(short)f2bf(a[3]);
    o[4]=(short)f2bf(b[0]); o[5]=(short)f2bf(b[1]); o[6]=(short)f2bf(b[2]); o[7]=(short)f2bf(b[3]);
    return o;
}

__device__ __forceinline__ void glds16(const void* g, void* l) {
    __builtin_amdgcn_global_load_lds((const __attribute__((address_space(1))) unsigned*)g,
                                     (__attribute__((address_space(3))) unsigned*)l, 16, 0, 0);
}

// ---------------- K0: zero counters ----------------
__global__ void init_kernel(int* __restrict__ counts) {
    if (threadIdx.x < 16) counts[threadIdx.x] = 0;   // counts[8] + counts2[8]
}

// ---------------- K1: router (fp32, exact top-2) ----------------
__global__ void router_kernel(const float* __restrict__ x, const float* __restrict__ wg,
                              int* __restrict__ topk_idx, float* __restrict__ topk_w,
                              int* __restrict__ counts) {
    int t = blockIdx.x;
    int lane = threadIdx.x;   // 64 threads = 1 wave
    const float* xr = x + (size_t)t * HD;
    float acc[NEXP];
#pragma unroll
    for (int e = 0; e < NEXP; ++e) acc[e] = 0.f;
#pragma unroll
    for (int i = 0; i < HD / 256; ++i) {
        int h = i * 256 + lane * 4;
        f32x4 xv = *(const f32x4*)(xr + h);
#pragma unroll
        for (int e = 0; e < NEXP; ++e) {
            f32x4 wv = *(const f32x4*)(wg + e * HD + h);
            acc[e] += xv[0]*wv[0] + xv[1]*wv[1] + xv[2]*wv[2] + xv[3]*wv[3];
        }
    }
#pragma unroll
    for (int e = 0; e < NEXP; ++e) {
#pragma unroll
        for (int s = 32; s > 0; s >>= 1) acc[e] += __shfl_xor(acc[e], s, 64);
    }
    if (lane == 0) {
        int b0 = 0; float l0 = acc[0];
#pragma unroll
        for (int e = 1; e < NEXP; ++e) if (acc[e] > l0) { l0 = acc[e]; b0 = e; }
        int b1 = (b0 == 0) ? 1 : 0; float l1 = acc[b1];
#pragma unroll
        for (int e = 0; e < NEXP; ++e) {
            if (e == b0 || e == b1) continue;
            if (acc[e] > l1) { l1 = acc[e]; b1 = e; }
        }
        float w0 = 1.f / (1.f + expf(l1 - l0));   // renormalized top-2 softmax
        float w1 = 1.f - w0;
        topk_idx[2 * t] = b0; topk_idx[2 * t + 1] = b1;
        topk_w[2 * t] = w0;  topk_w[2 * t + 1] = w1;
        atomicAdd(&counts[b0], 1);
        atomicAdd(&counts[b1], 1);
    }
}

// ---------------- K2: exclusive scan + pad rows ----------------
__global__ void scan_kernel(const int* __restrict__ counts, int* __restrict__ offsets,
                            int* __restrict__ rows) {
    if (threadIdx.x == 0) {
        int off = 0;
#pragma unroll
        for (int e = 0; e < NEXP; ++e) { offsets[e] = off; off += counts[e]; }
    }
    if (threadIdx.x < SLOT_PAD) rows[NSLOT + threadIdx.x] = 0;
}

// ---------------- K3: slot assignment ----------------
__global__ void assign_kernel(const int* __restrict__ topk_idx, const int* __restrict__ offsets,
                              int* __restrict__ counts2, int* __restrict__ rows,
                              int* __restrict__ slot_of) {
    int i = blockIdx.x * 256 + threadIdx.x;   // 0..4095
    int e = topk_idx[i];
    int pos = atomicAdd(&counts2[e], 1);
    int slot = offsets[e] + pos;
    rows[slot] = i >> 1;       // token id
    slot_of[i] = slot;
}

// ---------------- K4: generic fp32 -> bf16 (grid-stride over 8-elem units) ----------------
__global__ __launch_bounds__(256)
void cvt_bf_kernel(const float* __restrict__ src, u16* __restrict__ dst, int n8) {
    int stride = gridDim.x * 256;
    for (int i = blockIdx.x * 256 + threadIdx.x; i < n8; i += stride) {
        f32x4 v0 = ((const f32x4*)src)[2 * i];
        f32x4 v1 = ((const f32x4*)src)[2 * i + 1];
        ((s16x8*)dst)[i] = cvt8(v0, v1);
    }
}

// ---------------- K5: FAT kernel: fused GEMM1 (g,u)+SwiGLU -> h  ||  w2 fp32->bf16 ----------------
// 128x128 dual-B tile, BK=32, single-buffered m97 structure + T2 granule swizzle:
// physical granule = logical ^ ((row>>1)&3), applied on the GLOBAL source address at
// staging (glds writes linearly) and inverted on the ds_read byte offset (rule #21).
#define G1_BLOCKS (NEXP * (NTOK / 128) * (ID / 128))   // 3584
#define CVT2_BLOCKS 1024
__global__ __launch_bounds__(256, 2)
void gemm1_kernel(const u16* __restrict__ xbf, const u16* __restrict__ w1bf,
                  const u16* __restrict__ w3bf, const int* __restrict__ counts,
                  const int* __restrict__ offsets, const int* __restrict__ rows,
                  u16* __restrict__ hbuf,
                  const float* __restrict__ w2, u16* __restrict__ w2bf) {
    __shared__ u16 As[128][32];    // 8 KB
    __shared__ u16 B1s[128][32];   // 8 KB
    __shared__ u16 B3s[128][32];   // 8 KB

    if (blockIdx.x >= G1_BLOCKS) {
        // ---- side job: convert w2 to bf16 (overlaps with GEMM1 blocks) ----
        const int stride = CVT2_BLOCKS * 256;
        for (int i = (blockIdx.x - G1_BLOCKS) * 256 + threadIdx.x; i < WN / 8; i += stride) {
            f32x4 v0 = ((const f32x4*)w2)[2 * i];
            f32x4 v1 = ((const f32x4*)w2)[2 * i + 1];
            ((s16x8*)w2bf)[i] = cvt8(v0, v1);
        }
        return;
    }

    const int NT = ID / 128;      // 28
    int bid = blockIdx.x;
    int e = bid / (16 * NT);
    int rem = bid - e * (16 * NT);
    int mt = rem / NT;
    int nt = rem - mt * NT;
    int n_e = counts[e];
    int m0 = mt * 128;
    if (m0 >= n_e) return;
    int off = offsets[e];
    int n0 = nt * 128;

    int tid = threadIdx.x;
    int lane = tid & 63;
    int wid = tid >> 6;

    // staging: wave wid stages rows [32*wid,32*wid+32); lane -> LDS row srow(+16),
    // physical granule lane&3. Source granule = (lane&3) ^ ((srow>>1)&3).
    // Note (srow>>1)&3 == ((srow+16)>>1)&3, so one chunk serves both glds calls.
    int srow = wid * 32 + (lane >> 2);
    int chunk = ((lane & 3) ^ ((srow >> 1) & 3)) * 8;

    int tokA0 = rows[off + m0 + srow];
    int tokA1 = rows[off + m0 + srow + 16];
    const u16* srcA0 = xbf + (size_t)tokA0 * HD + chunk;
    const u16* srcA1 = xbf + (size_t)tokA1 * HD + chunk;
    const u16* srcB1a = w1bf + ((size_t)e * ID + n0 + srow) * HD + chunk;
    const u16* srcB1b = srcB1a + (size_t)16 * HD;
    const u16* srcB3a = w3bf + ((size_t)e * ID + n0 + srow) * HD + chunk;
    const u16* srcB3b = srcB3a + (size_t)16 * HD;

    f32x4 accg[4][4] = {}, accu[4][4] = {};
    int wm = (wid >> 1) * 64, wn = (wid & 1) * 64;
    int lr = lane & 15;
    // read side: logical granule lane>>4 lives at physical granule ^ ((row>>1)&3);
    // row = base16 + lr with base16 % 16 == 0 -> swizzle bits depend only on lr.
    int k8sw = ((lane >> 4) ^ ((lr >> 1) & 3)) * 8;

    for (int k0 = 0; k0 < HD; k0 += 32) {
        glds16(srcA0 + k0,  &As[wid * 32][0]);
        glds16(srcA1 + k0,  &As[wid * 32 + 16][0]);
        glds16(srcB1a + k0, &B1s[wid * 32][0]);
        glds16(srcB1b + k0, &B1s[wid * 32 + 16][0]);
        glds16(srcB3a + k0, &B3s[wid * 32][0]);
        glds16(srcB3b + k0, &B3s[wid * 32 + 16][0]);
        __syncthreads();
        s16x8 a[4], b1[4], b3[4];
#pragma unroll
        for (int f = 0; f < 4; ++f) {
            a[f]  = *(const s16x8*)&As[wm + f * 16 + lr][k8sw];
            b1[f] = *(const s16x8*)&B1s[wn + f * 16 + lr][k8sw];
            b3[f] = *(const s16x8*)&B3s[wn + f * 16 + lr][k8sw];
        }
#pragma unroll
        for (int fm = 0; fm < 4; ++fm)
#pragma unroll
            for (int fn = 0; fn < 4; ++fn) {
                accg[fm][fn] = __builtin_amdgcn_mfma_f32_16x16x32_bf16(a[fm], b1[fn], accg[fm][fn], 0, 0, 0);
                accu[fm][fn] = __builtin_amdgcn_mfma_f32_16x16x32_bf16(a[fm], b3[fn], accu[fm][fn], 0, 0, 0);
            }
        __syncthreads();
    }

    // epilogue: SwiGLU + bf16 store
    int lc = lane & 15;
    int lr4 = (lane >> 4) * 4;
#pragma unroll
    for (int fm = 0; fm < 4; ++fm) {
#pragma unroll
        for (int r = 0; r < 4; ++r) {
            int row = wm + fm * 16 + lr4 + r;
            if (m0 + row < n_e) {
                size_t base = (size_t)(off + m0 + row) * ID + n0 + wn;
#pragma unroll
                for (int fn = 0; fn < 4; ++fn) {
                    float g = accg[fm][fn][r];
                    float u = accu[fm][fn][r];
                    float hv = g * u / (1.f + expf(-g));   // silu(g)*u
                    hbuf[base + fn * 16 + lc] = f2bf(hv);
                }
            }
        }
    }
}

// ---------------- K6: GEMM2 h @ w2bf^T -> per-slot fp32, split-K x4, swizzled ----------------
__global__ __launch_bounds__(256, 2)
void gemm2_kernel(const u16* __restrict__ hbuf, const u16* __restrict__ w2bf,
                  const int* __restrict__ counts, const int* __restrict__ offsets,
                  float* __restrict__ out2) {
    const int NT = HD / 128;      // 8
    int bid = blockIdx.x;
    int e = bid / (16 * NT * KSPLIT);
    int rem = bid - e * (16 * NT * KSPLIT);
    int mt = rem / (NT * KSPLIT);
    int rem2 = rem - mt * (NT * KSPLIT);
    int nt = rem2 / KSPLIT;
    int ks = rem2 - nt * KSPLIT;
    int n_e = counts[e];
    int m0 = mt * 128;
    if (m0 >= n_e) return;
    int off = offsets[e];
    int n0 = nt * 128;
    int kbase = ks * KLEN;

    __shared__ u16 As[128][32];   // 8 KB
    __shared__ u16 Bs[128][32];   // 8 KB

    int tid = threadIdx.x;
    int lane = tid & 63;
    int wid = tid >> 6;

    int srow = wid * 32 + (lane >> 2);
    int chunk = ((lane & 3) ^ ((srow >> 1) & 3)) * 8;
    const u16* srcA0 = hbuf + (size_t)(off + m0 + srow) * ID + kbase + chunk;
    const u16* srcA1 = srcA0 + (size_t)16 * ID;
    const u16* srcB0 = w2bf + ((size_t)e * HD + n0 + srow) * ID + kbase + chunk;
    const u16* srcB1 = srcB0 + (size_t)16 * ID;

    f32x4 acc[4][4] = {};
    int wm = (wid >> 1) * 64, wn = (wid & 1) * 64;
    int lr = lane & 15;
    int k8sw = ((lane >> 4) ^ ((lr >> 1) & 3)) * 8;

    for (int k0 = 0; k0 < KLEN; k0 += 32) {
        glds16(srcA0 + k0, &As[wid * 32][0]);
        glds16(srcA1 + k0, &As[wid * 32 + 16][0]);
        glds16(srcB0 + k0, &Bs[wid * 32][0]);
        glds16(srcB1 + k0, &Bs[wid * 32 + 16][0]);
        __syncthreads();
        s16x8 a[4], b[4];
#pragma unroll
        for (int f = 0; f < 4; ++f) {
            a[f] = *(const s16x8*)&As[wm + f * 16 + lr][k8sw];
            b[f] = *(const s16x8*)&Bs[wn + f * 16 + lr][k8sw];
        }
#pragma unroll
        for (int fm = 0; fm < 4; ++fm)
#pragma unroll
            for (int fn = 0; fn < 4; ++fn)
                acc[fm][fn] = __builtin_amdgcn_mfma_f32_16x16x32_bf16(a[fm], b[fn], acc[fm][fn], 0, 0, 0);
        __syncthreads();
    }

    float* outp = out2 + (size_t)ks * NSLOT_ALLOC * HD;
    int lc = lane & 15;
    int lr4 = (lane >> 4) * 4;
#pragma unroll
    for (int fm = 0; fm < 4; ++fm) {
#pragma unroll
        for (int r = 0; r < 4; ++r) {
            int row = wm + fm * 16 + lr4 + r;
            if (m0 + row < n_e) {
                float* dst = outp + (size_t)(off + m0 + row) * HD + n0 + wn;
#pragma unroll
                for (int fn = 0; fn < 4; ++fn)
                    dst[fn * 16 + lc] = acc[fm][fn][r];
            }
        }
    }
}

// ---------------- K7: weighted combine (sums KSPLIT partials) ----------------
__global__ void combine_kernel(const float* __restrict__ out2, const int* __restrict__ slot_of,
                               const float* __restrict__ topk_w, float* __restrict__ y) {
    int i = blockIdx.x * 256 + threadIdx.x;   // over NTOK*HD/4
    int t = i >> 8;           // HD/4 = 256 float4 per token
    int c = i & 255;
    int s0 = slot_of[2 * t], s1 = slot_of[2 * t + 1];
    float w0 = topk_w[2 * t], w1 = topk_w[2 * t + 1];
    f32x4 o = {0.f, 0.f, 0.f, 0.f};
#pragma unroll
    for (int ks = 0; ks < KSPLIT; ++ks) {
        const float* p = out2 + (size_t)ks * NSLOT_ALLOC * HD;
        f32x4 a = ((const f32x4*)(p + (size_t)s0 * HD))[c];
        f32x4 b = ((const f32x4*)(p + (size_t)s1 * HD))[c];
#pragma unroll
        for (int j = 0; j < 4; ++j) o[j] += w0 * a[j] + w1 * b[j];
    }
    ((f32x4*)(y + (size_t)t * HD))[c] = o;
}

extern "C" void kernel_launch(void* const* d_in, const int* in_sizes, int n_in,
                              void* d_out, int out_size, void* d_ws, size_t ws_size,
                              hipStream_t stream) {
    (void)in_sizes; (void)n_in; (void)out_size; (void)ws_size;
    const float* x  = (const float*)d_in[0];
    const float* wg = (const float*)d_in[1];
    const float* w1 = (const float*)d_in[2];
    const float* w3 = (const float*)d_in[3];
    const float* w2 = (const float*)d_in[4];
    float* y = (float*)d_out;

    char* ws = (char*)d_ws;
    int*   counts   = (int*)(ws + 0);       // 8 ints
    int*   counts2  = (int*)(ws + 32);      // 8 ints
    int*   offsets  = (int*)(ws + 64);      // 8 ints
    int*   topk_idx = (int*)(ws + 128);                        // 4096 ints
    float* topk_w   = (float*)(ws + 128 + (size_t)NSLOT * 4);  // 4096 floats
    int*   rows     = (int*)(ws + 128 + (size_t)NSLOT * 8);    // 4224 ints
    int*   slot_of  = (int*)(ws + 128 + (size_t)NSLOT * 8 + (size_t)NSLOT_ALLOC * 4);
    size_t off_xbf = 128 + (size_t)NSLOT * 12 + (size_t)NSLOT_ALLOC * 4;
    off_xbf = (off_xbf + 255) & ~(size_t)255;
    u16* xbf = (u16*)(ws + off_xbf);
    size_t off_h = off_xbf + (size_t)NTOK * HD * 2;
    u16* hbuf = (u16*)(ws + off_h);
    size_t off_w1 = off_h + (size_t)NSLOT_ALLOC * ID * 2;
    u16* w1bf = (u16*)(ws + off_w1);
    size_t off_w3 = off_w1 + (size_t)WN * 2;
    u16* w3bf = (u16*)(ws + off_w3);
    size_t off_w2 = off_w3 + (size_t)WN * 2;
    u16* w2bf = (u16*)(ws + off_w2);
    size_t off_o2 = off_w2 + (size_t)WN * 2;
    float* out2 = (float*)(ws + off_o2);    // KSPLIT partial buffers

    init_kernel<<<1, 64, 0, stream>>>(counts);
    router_kernel<<<NTOK, 64, 0, stream>>>(x, wg, topk_idx, topk_w, counts);
    scan_kernel<<<1, 128, 0, stream>>>(counts, offsets, rows);
    assign_kernel<<<NSLOT / 256, 256, 0, stream>>>(topk_idx, offsets, counts2, rows, slot_of);
    cvt_bf_kernel<<<2048, 256, 0, stream>>>(x, xbf, NTOK * HD / 8);
    cvt_bf_kernel<<<2048, 256, 0, stream>>>(w1, w1bf, WN / 8);
    cvt_bf_kernel<<<2048, 256, 0, stream>>>(w3, w3bf, WN / 8);
    gemm1_kernel<<<G1_BLOCKS + CVT2_BLOCKS, 256, 0, stream>>>(xbf, w1bf, w3bf, counts, offsets, rows, hbuf, w2, w2bf);
    gemm2_kernel<<<NEXP * (NTOK / 128) * (HD / 128) * KSPLIT, 256, 0, stream>>>(hbuf, w2bf, counts, offsets, out2);
    combine_kernel<<<(NTOK * HD / 4) / 256, 256, 0, stream>>>(out2, slot_of, topk_w, y);
}